// Round 9
// baseline (22.153 us; speedup 1.0000x reference)
//
#include <hip/hip_runtime.h>
#include <math.h>

__device__ __forceinline__ float frcp(float x) { return __builtin_amdgcn_rcpf(x); }

// Exact area of CCW polygon ∩ axis-aligned box [-hw,hw]x[-hh,hh] via the
// per-edge coverage identity (validated R5-R8, absmax 0 vs jax reference):
//   Area = sum_e sigma_e * ( ∫ clamp(y_e(x), Y0, Y1) dx - Y0 * w_e ),
// integral over the edge's x-range clipped to the box's x-slab.
__device__ __forceinline__ float edge_area(float px, float py, float qx, float qy,
                                           float hw, float hh) {
    const float Y0 = -hh, Y1 = hh;
    float dx = qx - px, dy = qy - py;
    float lo = fmaxf(fminf(px, qx), -hw);
    float hi = fminf(fmaxf(px, qx),  hw);
    float w  = hi - lo;
    float dys = (fabsf(dy) > 1e-20f) ? dy : ((dy >= 0.f) ? 1e-20f : -1e-20f);
    float dxs = (fabsf(dx) > 1e-20f) ? dx : ((dx >= 0.f) ? 1e-20f : -1e-20f);
    float xdy = dx * frcp(dys);
    float m   = dy * frcp(dxs);
    float xa = fmaf(Y0 - py, xdy, px);
    float xb = fmaf(Y1 - py, xdy, px);
    float s0 = fminf(xa, xb), s1 = fmaxf(xa, xb);
    float u0 = fminf(fmaxf(s0, lo), hi);
    float u1 = fminf(fmaxf(s1, lo), hi);
    float yu0 = fmaf(m, u0 - px, py);
    float yu1 = fmaf(m, u1 - px, py);
    yu0 = fminf(fmaxf(yu0, Y0), Y1);
    yu1 = fminf(fmaxf(yu1, Y0), Y1);
    bool mpos = (dy >= 0.f) == (dx >= 0.f);
    float YL = mpos ? Y0 : Y1;
    float YR = mpos ? Y1 : Y0;
    float integral = YL * (u0 - lo)
                   + 0.5f * (yu0 + yu1) * (u1 - u0)
                   + YR * (hi - u1);
    float contrib = integral - Y0 * w;
    float res = (dx > 0.f) ? -contrib : contrib;
    return (w > 0.f) ? res : 0.f;
}

// one element: b1/b2 are 7 floats each -> 1 - iou3d
__device__ __forceinline__ float elem_loss(const float b1[7], const float b2[7]) {
    float x1 = b1[0], y1 = b1[1], z1 = b1[2], w1 = b1[3], h1 = b1[4], dz1 = b1[5], a1 = b1[6];
    float x2 = b2[0], y2 = b2[1], z2 = b2[2], w2 = b2[3], h2 = b2[4], dz2 = b2[5], a2 = b2[6];

    float zo = fmaxf(fminf(z1 + 0.5f * dz1, z2 + 0.5f * dz2)
                   - fmaxf(z1 - 0.5f * dz1, z2 - 0.5f * dz2), 0.0f);
    float vol1 = w1 * h1 * dz1;
    float vol2 = w2 * h2 * dz2;

    float sa = __sinf(a2), ca = __cosf(a2);
    float dxc = x1 - x2, dyc = y1 - y2;
    float tx =  dxc * ca + dyc * sa;
    float ty = -dxc * sa + dyc * ca;
    float ad = a1 - a2;
    float sd = __sinf(ad), cd = __cosf(ad);
    float hw1 = 0.5f * w1, hh1 = 0.5f * h1;
    float hw2 = 0.5f * w2, hh2 = 0.5f * h2;
    float ex = hw1 * cd, ey = hw1 * sd;
    float fx = -hh1 * sd, fy = hh1 * cd;
    float q0x = tx + ex + fx, q0y = ty + ey + fy;
    float q1x = tx - ex + fx, q1y = ty - ey + fy;
    float q2x = tx - ex - fx, q2y = ty - ey - fy;
    float q3x = tx + ex - fx, q3y = ty + ey - fy;

    float area = edge_area(q0x, q0y, q1x, q1y, hw2, hh2)
               + edge_area(q1x, q1y, q2x, q2y, hw2, hh2)
               + edge_area(q2x, q2y, q3x, q3y, hw2, hh2)
               + edge_area(q3x, q3y, q0x, q0y, hw2, hh2);
    area = fabsf(area);

    float inter3d = area * zo;
    float union3d = vol1 + vol2 - inter3d;
    return 1.0f - inter3d / union3d;
}

#define WAVES 4   // waves per 256-thread block; each wave: 128 elems, ONE pass

__global__ __launch_bounds__(256) void iou3d_loss_kernel(
    const float* __restrict__ pred, const float* __restrict__ target,
    float* __restrict__ partial, int N)
{
    // per-wave LDS tile: 896 floats pred + 896 floats target = 7168 B
    __shared__ float lds[WAVES][1792];
    const int lane = threadIdx.x & 63;
    const int wid  = threadIdx.x >> 6;
    const long gw  = (long)blockIdx.x * WAVES + wid;   // global wave id
    const long eb  = gw * 128;                         // 128 elems per wave
    const long totF2 = ((long)N * 7) >> 1;             // N*7 even for even N

    const float2* pred2 = (const float2*)pred;
    const float2* targ2 = (const float2*)target;
    float2* ldsP = (float2*)&lds[wid][0];
    float2* ldsT = (float2*)&lds[wid][896];

    float val = 0.f;

    const long f2b = (eb * 7) >> 1;                    // integer: eb even
    // ---- coalesced stage: 7 x dwordx2 per buffer (512B contiguous/instr) ----
    #pragma unroll
    for (int k = 0; k < 7; k++) {
        long idx = f2b + k * 64 + lane;
        bool ok = idx < totF2;
        float2 v = ok ? pred2[idx] : make_float2(0.f, 0.f);
        float2 u = ok ? targ2[idx] : make_float2(0.f, 0.f);
        ldsP[k * 64 + lane] = v;
        ldsT[k * 64 + lane] = u;
    }
    // wave-private tile: per-wave DS ordering via lgkmcnt, no __syncthreads
    float2 va[7], vb[7];
    #pragma unroll
    for (int j = 0; j < 7; j++) {
        va[j] = ldsP[7 * lane + j];   // floats [14*lane, 14*lane+14) = 2 elems
        vb[j] = ldsT[7 * lane + j];
    }
    float af[14], bf[14];
    #pragma unroll
    for (int j = 0; j < 7; j++) {
        af[2 * j] = va[j].x; af[2 * j + 1] = va[j].y;
        bf[2 * j] = vb[j].x; bf[2 * j + 1] = vb[j].y;
    }
    long e0 = eb + 2 * lane;
    if (e0 < N)     val += elem_loss(&af[0], &bf[0]);
    if (e0 + 1 < N) val += elem_loss(&af[7], &bf[7]);

    // ---- block reduction -> per-block partial (no global atomic) ----
    #pragma unroll
    for (int off = 32; off > 0; off >>= 1)
        val += __shfl_down(val, off, 64);
    __shared__ float wsum[WAVES];
    if (lane == 0) wsum[wid] = val;
    __syncthreads();
    if (threadIdx.x == 0) {
        float s = 0.f;
        #pragma unroll
        for (int q = 0; q < WAVES; q++) s += wsum[q];
        partial[blockIdx.x] = s;
    }
}

__global__ __launch_bounds__(1024) void iou3d_finalize_kernel(
    const float* __restrict__ partial, float* __restrict__ out, int nb, int N)
{
    float s = 0.f;
    for (int i = threadIdx.x; i < nb; i += 1024) s += partial[i];
    #pragma unroll
    for (int off = 32; off > 0; off >>= 1)
        s += __shfl_down(s, off, 64);
    __shared__ float ws[16];
    int lane = threadIdx.x & 63, wid = threadIdx.x >> 6;
    if (lane == 0) ws[wid] = s;
    __syncthreads();
    if (threadIdx.x == 0) {
        float t = 0.f;
        #pragma unroll
        for (int q = 0; q < 16; q++) t += ws[q];
        out[0] = (float)((double)t / (double)N);
    }
}

extern "C" void kernel_launch(void* const* d_in, const int* in_sizes, int n_in,
                              void* d_out, int out_size, void* d_ws, size_t ws_size,
                              hipStream_t stream) {
    const float* pred   = (const float*)d_in[0];
    const float* target = (const float*)d_in[1];
    int N = in_sizes[0] / 7;
    float* partial = (float*)d_ws;

    // each block = 4 waves x 128 elems = 512 elems
    int grid = (N + 511) / 512;
    iou3d_loss_kernel<<<grid, 256, 0, stream>>>(pred, target, partial, N);
    iou3d_finalize_kernel<<<1, 1024, 0, stream>>>(partial, (float*)d_out, grid, N);
}

// Round 10
// 20.106 us; speedup vs baseline: 1.1018x; 1.1018x over previous
//
#include <hip/hip_runtime.h>
#include <math.h>

__device__ __forceinline__ float frcp(float x) { return __builtin_amdgcn_rcpf(x); }

// Exact area of CCW polygon ∩ axis-aligned box [-hw,hw]x[-hh,hh] via the
// per-edge coverage identity (validated R5-R9, absmax 0 vs jax reference):
//   Area = sum_e sigma_e * ( ∫ clamp(y_e(x), Y0, Y1) dx - Y0 * w_e ),
// integral over the edge's x-range clipped to the box's x-slab.
__device__ __forceinline__ float edge_area(float px, float py, float qx, float qy,
                                           float hw, float hh) {
    const float Y0 = -hh, Y1 = hh;
    float dx = qx - px, dy = qy - py;
    float lo = fmaxf(fminf(px, qx), -hw);
    float hi = fminf(fmaxf(px, qx),  hw);
    float w  = hi - lo;
    float dys = (fabsf(dy) > 1e-20f) ? dy : ((dy >= 0.f) ? 1e-20f : -1e-20f);
    float dxs = (fabsf(dx) > 1e-20f) ? dx : ((dx >= 0.f) ? 1e-20f : -1e-20f);
    float xdy = dx * frcp(dys);
    float m   = dy * frcp(dxs);
    float xa = fmaf(Y0 - py, xdy, px);
    float xb = fmaf(Y1 - py, xdy, px);
    float s0 = fminf(xa, xb), s1 = fmaxf(xa, xb);
    float u0 = fminf(fmaxf(s0, lo), hi);
    float u1 = fminf(fmaxf(s1, lo), hi);
    float yu0 = fmaf(m, u0 - px, py);
    float yu1 = fmaf(m, u1 - px, py);
    yu0 = fminf(fmaxf(yu0, Y0), Y1);
    yu1 = fminf(fmaxf(yu1, Y0), Y1);
    bool mpos = (dy >= 0.f) == (dx >= 0.f);
    float YL = mpos ? Y0 : Y1;
    float YR = mpos ? Y1 : Y0;
    float integral = YL * (u0 - lo)
                   + 0.5f * (yu0 + yu1) * (u1 - u0)
                   + YR * (hi - u1);
    float contrib = integral - Y0 * w;
    float res = (dx > 0.f) ? -contrib : contrib;
    return (w > 0.f) ? res : 0.f;
}

// one element: b1/b2 are 7 floats each -> 1 - iou3d
__device__ __forceinline__ float elem_loss(const float b1[7], const float b2[7]) {
    float x1 = b1[0], y1 = b1[1], z1 = b1[2], w1 = b1[3], h1 = b1[4], dz1 = b1[5], a1 = b1[6];
    float x2 = b2[0], y2 = b2[1], z2 = b2[2], w2 = b2[3], h2 = b2[4], dz2 = b2[5], a2 = b2[6];

    float zo = fmaxf(fminf(z1 + 0.5f * dz1, z2 + 0.5f * dz2)
                   - fmaxf(z1 - 0.5f * dz1, z2 - 0.5f * dz2), 0.0f);
    float vol1 = w1 * h1 * dz1;
    float vol2 = w2 * h2 * dz2;

    float sa = __sinf(a2), ca = __cosf(a2);
    float dxc = x1 - x2, dyc = y1 - y2;
    float tx =  dxc * ca + dyc * sa;
    float ty = -dxc * sa + dyc * ca;
    float ad = a1 - a2;
    float sd = __sinf(ad), cd = __cosf(ad);
    float hw1 = 0.5f * w1, hh1 = 0.5f * h1;
    float hw2 = 0.5f * w2, hh2 = 0.5f * h2;
    float ex = hw1 * cd, ey = hw1 * sd;
    float fx = -hh1 * sd, fy = hh1 * cd;
    float q0x = tx + ex + fx, q0y = ty + ey + fy;
    float q1x = tx - ex + fx, q1y = ty - ey + fy;
    float q2x = tx - ex - fx, q2y = ty - ey - fy;
    float q3x = tx + ex - fx, q3y = ty + ey - fy;

    float area = edge_area(q0x, q0y, q1x, q1y, hw2, hh2)
               + edge_area(q1x, q1y, q2x, q2y, hw2, hh2)
               + edge_area(q2x, q2y, q3x, q3y, hw2, hh2)
               + edge_area(q3x, q3y, q0x, q0y, hw2, hh2);
    area = fabsf(area);

    float inter3d = area * zo;
    float union3d = vol1 + vol2 - inter3d;
    return 1.0f - inter3d * frcp(union3d);   // fast rcp: ~1e-7 rel err vs 2e-2 threshold
}

#define WAVES 4        // waves per 256-thread block
#define TILES 4        // tiles per wave (software pipelined)
#define TILE_ELEMS 128 // elems per tile (2 per lane)

__global__ __launch_bounds__(256) void iou3d_loss_kernel(
    const float* __restrict__ pred, const float* __restrict__ target,
    float* __restrict__ partial, int N)
{
    // per-wave LDS tile: 896 floats pred + 896 floats target = 7168 B
    __shared__ float lds[WAVES][1792];
    const int lane = threadIdx.x & 63;
    const int wid  = threadIdx.x >> 6;
    const long gw  = (long)blockIdx.x * WAVES + wid;   // global wave id
    const long tile0 = gw * TILES;                     // first tile of this wave
    const long totF2 = ((long)N * 7) >> 1;             // N*7/2 (N even)

    const float2* pred2 = (const float2*)pred;
    const float2* targ2 = (const float2*)target;
    float2* ldsP = (float2*)&lds[wid][0];
    float2* ldsT = (float2*)&lds[wid][896];

    float val = 0.f;

    // ---- prologue: prefetch tile 0 into registers (14 coalesced dwordx2) ----
    float2 pa[7], pb[7];
    {
        const long f2b = tile0 * 448;  // 448 float2 per tile per buffer
        #pragma unroll
        for (int k = 0; k < 7; k++) {
            long idx = f2b + k * 64 + lane;
            bool ok = idx < totF2;
            pa[k] = ok ? pred2[idx] : make_float2(0.f, 0.f);
            pb[k] = ok ? targ2[idx] : make_float2(0.f, 0.f);
        }
    }

    // ---- pipelined tile loop: ds_write(cur) -> prefetch(next) -> ds_read -> compute ----
    // Same-wave DS ops execute in order, so the single wave-private LDS buffer
    // is reused safely with no barriers; next tile's global loads are in
    // flight during this tile's compute.
    #pragma unroll 1
    for (int t = 0; t < TILES; t++) {
        #pragma unroll
        for (int k = 0; k < 7; k++) {
            ldsP[k * 64 + lane] = pa[k];
            ldsT[k * 64 + lane] = pb[k];
        }
        if (t + 1 < TILES) {
            const long f2b = (tile0 + t + 1) * 448;
            #pragma unroll
            for (int k = 0; k < 7; k++) {
                long idx = f2b + k * 64 + lane;
                bool ok = idx < totF2;
                pa[k] = ok ? pred2[idx] : make_float2(0.f, 0.f);
                pb[k] = ok ? targ2[idx] : make_float2(0.f, 0.f);
            }
        }
        float af[14], bf[14];
        #pragma unroll
        for (int j = 0; j < 7; j++) {
            float2 va = ldsP[7 * lane + j];   // floats [14*lane, 14*lane+14)
            float2 vb = ldsT[7 * lane + j];
            af[2 * j] = va.x; af[2 * j + 1] = va.y;
            bf[2 * j] = vb.x; bf[2 * j + 1] = vb.y;
        }
        long e0 = (tile0 + t) * TILE_ELEMS + 2 * lane;
        if (e0 < N)     val += elem_loss(&af[0], &bf[0]);
        if (e0 + 1 < N) val += elem_loss(&af[7], &bf[7]);
    }

    // ---- block reduction -> per-block partial ----
    #pragma unroll
    for (int off = 32; off > 0; off >>= 1)
        val += __shfl_down(val, off, 64);
    __shared__ float wsum[WAVES];
    if (lane == 0) wsum[wid] = val;
    __syncthreads();
    if (threadIdx.x == 0) {
        float s = 0.f;
        #pragma unroll
        for (int q = 0; q < WAVES; q++) s += wsum[q];
        partial[blockIdx.x] = s;
    }
}

__global__ __launch_bounds__(1024) void iou3d_finalize_kernel(
    const float* __restrict__ partial, float* __restrict__ out, int nb, int N)
{
    float s = 0.f;
    for (int i = threadIdx.x; i < nb; i += 1024) s += partial[i];
    #pragma unroll
    for (int off = 32; off > 0; off >>= 1)
        s += __shfl_down(s, off, 64);
    __shared__ float ws[16];
    int lane = threadIdx.x & 63, wid = threadIdx.x >> 6;
    if (lane == 0) ws[wid] = s;
    __syncthreads();
    if (threadIdx.x == 0) {
        float t = 0.f;
        #pragma unroll
        for (int q = 0; q < 16; q++) t += ws[q];
        out[0] = (float)((double)t / (double)N);
    }
}

extern "C" void kernel_launch(void* const* d_in, const int* in_sizes, int n_in,
                              void* d_out, int out_size, void* d_ws, size_t ws_size,
                              hipStream_t stream) {
    const float* pred   = (const float*)d_in[0];
    const float* target = (const float*)d_in[1];
    int N = in_sizes[0] / 7;
    float* partial = (float*)d_ws;

    long tiles = ((long)N + TILE_ELEMS - 1) / TILE_ELEMS;
    long waves = (tiles + TILES - 1) / TILES;
    int grid = (int)((waves + WAVES - 1) / WAVES);
    iou3d_loss_kernel<<<grid, 256, 0, stream>>>(pred, target, partial, N);
    iou3d_finalize_kernel<<<1, 1024, 0, stream>>>(partial, (float*)d_out, grid, N);
}